// Round 2
// baseline (634.863 us; speedup 1.0000x reference)
//
#include <hip/hip_runtime.h>
#include <cstdint>
#include <cstddef>

#define H_      128
#define NITEMS  50000
#define NSEQ    704            // 64 cur + 640 frd sequences, all length 20
#define NTOK    (NSEQ * 20)    // 14080
#define NPAD    50048          // items padded to multiple of 128 for GEMM tiles

typedef __attribute__((ext_vector_type(8))) short short8;
typedef __attribute__((ext_vector_type(4))) float f32x4;

__device__ __forceinline__ unsigned short f2bf(float f) {
  unsigned int u = __float_as_uint(f);
  u += 0x7FFF + ((u >> 16) & 1);   // round-to-nearest-even
  return (unsigned short)(u >> 16);
}
__device__ __forceinline__ float sigmoidf_(float x) {
  return 1.0f / (1.0f + __expf(-x));
}

// ---------------------------------------------------------------------------
// kA: gi[token][384] = v_emb[id] @ W_ih^T + b_ih for all 14080 tokens (fp32).
__global__ void __launch_bounds__(384) kA_gi(const int* __restrict__ cur,
                                             const int* __restrict__ frd,
                                             const float* __restrict__ vemb,
                                             const float* __restrict__ Wih,
                                             const float* __restrict__ bih,
                                             float* __restrict__ gi) {
  __shared__ float xs[16 * 128];
  __shared__ int ids[16];
  int tid = threadIdx.x;
  int tok0 = blockIdx.x * 16;
  if (tid < 16) {
    int tok = tok0 + tid;
    int seq = tok / 20, tt = tok % 20;
    ids[tid] = (seq < 64) ? cur[seq * 20 + tt] : frd[(seq - 64) * 20 + tt];
  }
  __syncthreads();
  for (int idx = tid; idx < 512; idx += 384) {
    int i = idx >> 5, kc = idx & 31;
    *(float4*)&xs[i * 128 + kc * 4] =
        *(const float4*)&vemb[(size_t)ids[i] * 128 + kc * 4];
  }
  __syncthreads();
  int j = tid;  // 0..383
  float acc[16];
#pragma unroll
  for (int i = 0; i < 16; i++) acc[i] = 0.f;
  const float* wrow = Wih + (size_t)j * 128;
  for (int kc = 0; kc < 32; kc++) {
    float4 w4 = *(const float4*)(wrow + kc * 4);
#pragma unroll
    for (int i = 0; i < 16; i++) {
      float4 x4 = *(const float4*)&xs[i * 128 + kc * 4];
      acc[i] += w4.x * x4.x + w4.y * x4.y + w4.z * x4.z + w4.w * x4.w;
    }
  }
  float bb = bih[j];
#pragma unroll
  for (int i = 0; i < 16; i++)
    gi[(size_t)(tok0 + i) * 384 + j] = acc[i] + bb;
}

// ---------------------------------------------------------------------------
// kB: GRU recurrence, fp32, ONE sequence per block (704 blocks, 6 waves each)
// so ~2-3 blocks/CU cover each other's barrier stalls. Thread j keeps W_hh
// row j in registers; h broadcast from LDS.
__global__ void __launch_bounds__(384) kB_gru(const float* __restrict__ Whh,
                                              const float* __restrict__ bhh,
                                              const float* __restrict__ gi,
                                              float* __restrict__ out_h) {
  __shared__ float hb[128];
  __shared__ float pre[256];
  __shared__ float gin[128];
  __shared__ float ghn[128];
  int j = threadIdx.x;
  int seq = blockIdx.x;
  float4 wv[32];
  const float4* wr = (const float4*)(Whh + (size_t)j * 128);
#pragma unroll
  for (int kc = 0; kc < 32; kc++) wv[kc] = wr[kc];
  float bb = bhh[j];
  if (j < 128) hb[j] = 0.f;
  __syncthreads();
  for (int t = 0; t < 20; t++) {
    float acc = bb;  // gh_j = W_hh[j] . h + b_hh[j]
#pragma unroll
    for (int kc = 0; kc < 32; kc++) {
      float4 h4 = *(const float4*)&hb[kc * 4];
      float4 w4 = wv[kc];
      acc += w4.x * h4.x + w4.y * h4.y + w4.z * h4.z + w4.w * h4.w;
    }
    float gv = gi[(size_t)(seq * 20 + t) * 384 + j];
    if (j < 256) pre[j] = gv + acc;
    else { gin[j - 256] = gv; ghn[j - 256] = acc; }
    __syncthreads();
    if (j < 128) {
      float r = sigmoidf_(pre[j]);
      float z = sigmoidf_(pre[128 + j]);
      float n = tanhf(gin[j] + r * ghn[j]);
      float hN = (1.f - z) * n + z * hb[j];
      hb[j] = hN;
      out_h[(size_t)(seq * 20 + t) * 128 + j] = hN;
    }
    __syncthreads();
  }
}

// ---------------------------------------------------------------------------
// kC: fused attention pipeline (old k4+k5+k6+k7+k8). One block per b.
// Produces act[1280][128] (uint = 2 bf16): cols 0..127 = hs, 128..255 = hf.
__global__ void __launch_bounds__(256) kC_attn(const int* __restrict__ users,
                                               const int* __restrict__ frd,
                                               const float* __restrict__ vemb,
                                               const float* __restrict__ uemb,
                                               const float* __restrict__ outh,
                                               unsigned int* __restrict__ act) {
  __shared__ float hs[20 * 132];
  __shared__ float buf[20 * 132];
  __shared__ float sc[400];
  __shared__ float sim[200];   // sim_raw [s][t]
  __shared__ float s1[200];    // sim1 then reused
  __shared__ float sfin[200];
  __shared__ float sess[10 * 128];
  __shared__ float us[128];
  __shared__ float dt[20];
  __shared__ float wl[20];
  __shared__ int pres[10];
  int tid = threadIdx.x;
  int b = blockIdx.x;

  // load hs (query) + user embedding
  for (int idx = tid; idx < 640; idx += 256) {
    int row = idx >> 5, kc = idx & 31;
    *(float4*)&hs[row * 132 + kc * 4] =
        *(const float4*)&outh[(size_t)(b * 20 + row) * 128 + kc * 4];
  }
  if (tid < 128) us[tid] = uemb[(size_t)users[b] * 128 + tid];
  if (tid < 10) pres[tid] = 0;
  __syncthreads();

  // ---- scores: sim[s][t] = max_l hs[t].enc[s][l]
  for (int s = 0; s < 10; s++) {
    int eseq = 64 + b * 10 + s;
    for (int idx = tid; idx < 640; idx += 256) {
      int row = idx >> 5, kc = idx & 31;
      *(float4*)&buf[row * 132 + kc * 4] =
          *(const float4*)&outh[(size_t)(eseq * 20 + row) * 128 + kc * 4];
    }
    __syncthreads();
    for (int idx = tid; idx < 400; idx += 256) {
      int t = idx / 20, l = idx % 20;
      float acc = 0.f;
#pragma unroll
      for (int kc = 0; kc < 32; kc++) {
        float4 q4 = *(const float4*)&hs[t * 132 + kc * 4];
        float4 e4 = *(const float4*)&buf[l * 132 + kc * 4];
        acc += q4.x * e4.x + q4.y * e4.y + q4.z * e4.z + q4.w * e4.w;
      }
      sc[idx] = acc;
    }
    __syncthreads();
    if (tid < 20) {
      float m = sc[tid * 20];
      for (int l = 1; l < 20; l++) m = fmaxf(m, sc[tid * 20 + l]);
      sim[s * 20 + tid] = m;
    }
    __syncthreads();
  }

  // ---- user-attention session embeddings
  for (int s = 0; s < 10; s++) {
    for (int idx = tid; idx < 640; idx += 256) {
      int row = idx >> 5, kc = idx & 31;
      int fid = frd[(size_t)(b * 10 + s) * 20 + row];
      *(float4*)&buf[row * 132 + kc * 4] =
          *(const float4*)&vemb[(size_t)fid * 128 + kc * 4];
    }
    __syncthreads();
    if (tid < 20) {
      float acc = 0.f;
      for (int kc = 0; kc < 32; kc++) {
        float4 u4 = *(const float4*)&us[kc * 4];
        float4 f4 = *(const float4*)&buf[tid * 132 + kc * 4];
        acc += u4.x * f4.x + u4.y * f4.y + u4.z * f4.z + u4.w * f4.w;
      }
      dt[tid] = acc;
    }
    __syncthreads();
    if (tid < 20) {
      float mx = -3.4e38f;
      for (int l = 0; l < 20; l++) mx = fmaxf(mx, dt[l]);
      float sum = 0.f;
      for (int l = 0; l < 20; l++) sum += __expf(dt[l] - mx);
      wl[tid] = __expf(dt[tid] - mx) / sum;
    }
    __syncthreads();
    if (tid < 128) {
      float acc = 0.f;
      for (int l = 0; l < 20; l++) acc += wl[l] * buf[l * 132 + tid];
      sess[s * 128 + tid] = acc;
    }
    __syncthreads();
  }

  // ---- softmax over s, top-2 preserve, double masked softmax
  if (tid < 20) {
    int t = tid;
    float mx = -3.4e38f;
    for (int s = 0; s < 10; s++) mx = fmaxf(mx, sim[s * 20 + t]);
    float sum = 0.f;
    for (int s = 0; s < 10; s++) sum += __expf(sim[s * 20 + t] - mx);
    float inv = 1.0f / sum;
    float v1 = -1.f, v2 = -1.f; int i1 = 0, i2 = 0;
    for (int s = 0; s < 10; s++) {
      float v = __expf(sim[s * 20 + t] - mx) * inv;
      s1[s * 20 + t] = v;
      if (v > v1) { v2 = v1; i2 = i1; v1 = v; i1 = s; }
      else if (v > v2) { v2 = v; i2 = s; }
    }
    atomicOr(&pres[i1], 1);
    atomicOr(&pres[i2], 1);
  }
  __syncthreads();
  if (tid < 20) {
    int t = tid;
    float mx = -3.4e38f;
    for (int s = 0; s < 10; s++) if (pres[s]) mx = fmaxf(mx, s1[s * 20 + t]);
    float sum = 0.f;
    for (int s = 0; s < 10; s++) if (pres[s]) sum += __expf(s1[s * 20 + t] - mx);
    float inv = 1.f / sum;
    float mx2 = -3.4e38f;
    for (int s = 0; s < 10; s++)
      if (pres[s]) mx2 = fmaxf(mx2, __expf(s1[s * 20 + t] - mx) * inv);
    float sum2 = 0.f;
    for (int s = 0; s < 10; s++)
      if (pres[s]) sum2 += __expf(__expf(s1[s * 20 + t] - mx) * inv - mx2);
    float inv2 = 1.f / sum2;
    for (int s = 0; s < 10; s++) {
      float o = 0.f;
      if (pres[s]) o = __expf(__expf(s1[s * 20 + t] - mx) * inv - mx2) * inv2;
      sfin[s * 20 + t] = o;
    }
  }
  __syncthreads();

  // ---- hf + pack act rows (bf16 pairs): cols 0..63 = hs, 64..127 = hf
  for (int idx = tid; idx < 2560; idx += 256) {
    int t = idx >> 7, u = idx & 127;
    float a0, a1;
    if (u < 64) {
      a0 = hs[t * 132 + u * 2];
      a1 = hs[t * 132 + u * 2 + 1];
    } else {
      int h0 = (u - 64) * 2;
      float s0 = 0.f, s1v = 0.f;
#pragma unroll
      for (int s = 0; s < 10; s++) {
        float w = sfin[s * 20 + t];
        s0 += w * sess[s * 128 + h0];
        s1v += w * sess[s * 128 + h0 + 1];
      }
      a0 = s0; a1 = s1v;
    }
    act[(size_t)(b * 20 + t) * 128 + u] =
        (unsigned)f2bf(a0) | ((unsigned)f2bf(a1) << 16);
  }
}

// ---------------------------------------------------------------------------
// kD: logits[1280][50000] = act(bf16) @ W^T + b, reading out1_w fp32 directly.
// B tile (128n x 256k bf16) converted+staged to LDS once (XOR-32 swizzle);
// A-fragments loaded straight from global (L2-hot) into registers.
// ONE barrier total -> compiler free to interleave MFMA with loads (vmcnt).
__global__ void __launch_bounds__(256) kD_gemm(const unsigned short* __restrict__ act,
                                               const float* __restrict__ w1,
                                               const float* __restrict__ bias,
                                               float* __restrict__ out) {
  __shared__ __align__(16) unsigned short Bs[128 * 256];  // 64 KB, xor-swizzled
  int tid = threadIdx.x;
  int w = tid >> 6, lane = tid & 63;
  int q = (lane >> 4) & 3, c = lane & 15;
  int wm = w >> 1, wn = w & 1;
  int nb0 = blockIdx.x * 128;

  // stage + convert B tile: 128 rows x 64 float4-chunks (cols 0..127,256..383)
#pragma unroll
  for (int it = 0; it < 32; it++) {
    int idx = it * 256 + tid;          // 0..8191
    int n_l = idx >> 6, ch = idx & 63; // row in tile, float4 chunk of eff-256
    int n = nb0 + n_l;
    int c4 = ch * 4;
    int src = (c4 < 128) ? c4 : (c4 + 128);
    float4 f;
    if (n < NITEMS) f = *(const float4*)&w1[(size_t)n * 384 + src];
    else { f.x = 0.f; f.y = 0.f; f.z = 0.f; f.w = 0.f; }
    unsigned int lo = (unsigned)f2bf(f.x) | ((unsigned)f2bf(f.y) << 16);
    unsigned int hi = (unsigned)f2bf(f.z) | ((unsigned)f2bf(f.w) << 16);
    int kc16 = ch >> 1, half = ch & 1;
    int p = kc16 ^ (n_l & 31);
    *(uint2*)&Bs[n_l * 256 + p * 8 + half * 4] = make_uint2(lo, hi);
  }

  float bs[4]; int okn[4]; int ncol[4];
#pragma unroll
  for (int nt = 0; nt < 4; nt++) {
    int n = nb0 + wn * 64 + nt * 16 + c;
    ncol[nt] = n;
    okn[nt] = (n < NITEMS);
    bs[nt] = (n < NITEMS) ? bias[n] : 0.f;
  }
  __syncthreads();  // the ONLY barrier

  for (int mc = 0; mc < 10; mc++) {
    f32x4 acc[4][4];
#pragma unroll
    for (int mt = 0; mt < 4; mt++)
#pragma unroll
      for (int nt = 0; nt < 4; nt++) {
        f32x4 z = {0.f, 0.f, 0.f, 0.f};
        acc[mt][nt] = z;
      }
#pragma unroll
    for (int kf = 0; kf < 8; kf++) {
      short8 afr[4];
#pragma unroll
      for (int mt = 0; mt < 4; mt++) {
        int row = mc * 128 + wm * 64 + mt * 16 + c;
        afr[mt] = *(const short8*)&act[(size_t)row * 256 + kf * 32 + q * 8];
      }
      short8 bfr[4];
#pragma unroll
      for (int nt = 0; nt < 4; nt++) {
        int n_l = wn * 64 + nt * 16 + c;
        int slot = n_l * 32 + ((kf * 4 + q) ^ (n_l & 31));
        bfr[nt] = *(const short8*)&Bs[slot * 8];
      }
#pragma unroll
      for (int mt = 0; mt < 4; mt++)
#pragma unroll
        for (int nt = 0; nt < 4; nt++)
          acc[mt][nt] = __builtin_amdgcn_mfma_f32_16x16x32_bf16(afr[mt], bfr[nt], acc[mt][nt], 0, 0, 0);
    }
    // epilogue: D row = q*4+r, col = c
#pragma unroll
    for (int nt = 0; nt < 4; nt++) {
      if (okn[nt]) {
#pragma unroll
        for (int mt = 0; mt < 4; mt++) {
          int m = mc * 128 + wm * 64 + mt * 16 + q * 4;
#pragma unroll
          for (int r = 0; r < 4; r++)
            out[(size_t)(m + r) * NITEMS + ncol[nt]] = acc[mt][nt][r] + bs[nt];
        }
      }
    }
  }
}

// ---------------------------------------------------------------------------
extern "C" void kernel_launch(void* const* d_in, const int* in_sizes, int n_in,
                              void* d_out, int out_size, void* d_ws, size_t ws_size,
                              hipStream_t stream) {
  const int*   users = (const int*)d_in[0];
  const int*   cur   = (const int*)d_in[1];
  // d_in[2] = hist_sess (unused by reference)
  const int*   frd   = (const int*)d_in[3];
  // d_in[4] = cur_sess_len (unused by reference)
  const float* vemb  = (const float*)d_in[5];
  const float* uemb  = (const float*)d_in[6];
  const float* Wih   = (const float*)d_in[7];
  const float* Whh   = (const float*)d_in[8];
  const float* bih   = (const float*)d_in[9];
  const float* bhh   = (const float*)d_in[10];
  const float* w1    = (const float*)d_in[11];
  const float* b1    = (const float*)d_in[12];
  float* out = (float*)d_out;

  char* ws = (char*)d_ws;
  size_t off = 0;
  auto alloc = [&](size_t bytes) -> void* {
    void* p = ws + off;
    off = (off + bytes + 255) & ~(size_t)255;
    return p;
  };
  float*        gi   = (float*)alloc((size_t)NTOK * 384 * 4);   // 21.6 MB
  float*        outh = (float*)alloc((size_t)NTOK * 128 * 4);   // 7.2 MB
  unsigned int* act  = (unsigned int*)alloc((size_t)1280 * 128 * 4);

  kA_gi<<<NTOK / 16, 384, 0, stream>>>(cur, frd, vemb, Wih, bih, gi);
  kB_gru<<<NSEQ, 384, 0, stream>>>(Whh, bhh, gi, outh);
  kC_attn<<<64, 256, 0, stream>>>(users, frd, vemb, uemb, outh, act);
  kD_gemm<<<NPAD / 128, 256, 0, stream>>>((const unsigned short*)act, w1, b1, out);
}